// Round 6
// baseline (1255.860 us; speedup 1.0000x reference)
//
#include <hip/hip_runtime.h>
#include <hip/hip_bf16.h>
#include <math.h>

#define F_IN 128
#define F_HID 64
#define F_OUT 40
#define BN_EPS 1e-5f

typedef __attribute__((ext_vector_type(8))) short short8;
typedef __attribute__((ext_vector_type(4))) float f32x4;

__device__ __forceinline__ float bflo(unsigned u) { return __uint_as_float(u << 16); }
__device__ __forceinline__ float bfhi(unsigned u) { return __uint_as_float(u & 0xffff0000u); }
__device__ __forceinline__ unsigned pack2(float a, float b) {
    __hip_bfloat162 p;
    p.x = __float2bfloat16(a);
    p.y = __float2bfloat16(b);
    return *(unsigned*)&p;
}

// ============ CSR build via 2-level LDS counting sort.
// r1: global atomics write through memory-side at 32B/op -> never on hot path.
// r4: node reordering destroys L2 residency -> natural order everywhere.
// r5: per-node lockstep gather is latency-chain-bound (VALU 27%, HBM 15%)
//     -> conv rewritten edge-parallel with LDS f32 atomics (ds_add_f32).

// ---- pass 1: per-(bucket, block) coarse histogram ----
__global__ __launch_bounds__(256) void k_hist(const int* __restrict__ col, int E,
                                              int chunk, int nblk, int NB,
                                              int* __restrict__ bh) {
    __shared__ int hist[512];
    int t = threadIdx.x, blk = blockIdx.x;
    for (int i = t; i < NB; i += 256) hist[i] = 0;
    __syncthreads();
    int e0 = blk * chunk, e1 = min(E, e0 + chunk);
    for (int e = e0 + t; e < e1; e += 256)
        atomicAdd(&hist[col[e] >> 8], 1);
    __syncthreads();
    for (int i = t; i < NB; i += 256)
        bh[(size_t)i * nblk + blk] = hist[i];
}

// ---- pass 2: per-bucket scan of its nblk cells; 1 cursor atomic per bucket. ----
__global__ __launch_bounds__(256) void k_alloc(int* __restrict__ bh,
                                               int* __restrict__ bb,
                                               int* __restrict__ bt,
                                               int* __restrict__ cursor, int nblk) {
    int t = threadIdx.x, bu = blockIdx.x;
    int lane = t & 63, wv = t >> 6;
    size_t base_i = (size_t)bu * nblk;
    int i0 = 2 * t, i1 = 2 * t + 1;
    int a = (i0 < nblk) ? bh[base_i + i0] : 0;
    int b = (i1 < nblk) ? bh[base_i + i1] : 0;
    int p = a + b;
    int scan = p;
    #pragma unroll
    for (int o = 1; o < 64; o <<= 1) {
        int tt = __shfl_up(scan, o);
        if (lane >= o) scan += tt;
    }
    __shared__ int wsum[4];
    if (lane == 63) wsum[wv] = scan;
    __syncthreads();
    if (t == 0) {
        int s0 = wsum[0], s1 = wsum[1], s2 = wsum[2], s3 = wsum[3];
        int total = s0 + s1 + s2 + s3;
        int base = atomicAdd(cursor, total);
        bb[bu] = base;
        bt[bu] = total;
        wsum[0] = base; wsum[1] = base + s0;
        wsum[2] = base + s0 + s1; wsum[3] = base + s0 + s1 + s2;
    }
    __syncthreads();
    int excl = wsum[wv] + scan - p;   // absolute start of cell i0
    if (i0 < nblk) bh[base_i + i0] = excl;
    if (i1 < nblk) bh[base_i + i1] = excl + a;
}

// ---- pass 3: scatter edges into bucket-partitioned order via LDS cursors. ----
__global__ __launch_bounds__(256) void k_scatter(const int* __restrict__ row,
                                                 const int* __restrict__ col,
                                                 int E, int chunk, int nblk, int NB,
                                                 const int* __restrict__ bh,
                                                 unsigned* __restrict__ bpk) {
    __shared__ int cur[512];
    int t = threadIdx.x, blk = blockIdx.x;
    for (int i = t; i < NB; i += 256) cur[i] = bh[(size_t)i * nblk + blk];
    __syncthreads();
    int e0 = blk * chunk, e1 = min(E, e0 + chunk);
    for (int e = e0 + t; e < e1; e += 256) {
        int c = col[e];
        int pos = atomicAdd(&cur[c >> 8], 1);
        bpk[pos] = ((unsigned)row[e] << 8) | (unsigned)(c & 255);
    }
}

// ---- pass 4: per-bucket fine histogram + scan -> off/endp/dinv; place srcs
//      AND d8 (dst-within-bucket byte, consumed by the edge-parallel convs). ----
__global__ __launch_bounds__(256) void k_fine(const unsigned* __restrict__ bpk,
                                              const int* __restrict__ bb,
                                              const int* __restrict__ bt,
                                              int* __restrict__ off,
                                              int* __restrict__ endp,
                                              float* __restrict__ dinv,
                                              int* __restrict__ srcs,
                                              unsigned char* __restrict__ d8, int n) {
    __shared__ int fine[256];
    __shared__ int wsum[4];
    int t = threadIdx.x, bu = blockIdx.x;
    int lane = t & 63, wv = t >> 6;
    fine[t] = 0;
    __syncthreads();
    int base = bb[bu], tot = bt[bu];
    for (int i = t; i < tot; i += 256)
        atomicAdd(&fine[bpk[base + i] & 255], 1);
    __syncthreads();
    int d = fine[t];
    int scan = d;
    #pragma unroll
    for (int o = 1; o < 64; o <<= 1) {
        int tt = __shfl_up(scan, o);
        if (lane >= o) scan += tt;
    }
    if (lane == 63) wsum[wv] = scan;
    __syncthreads();
    if (t == 0) {
        int s0 = wsum[0], s1 = wsum[1], s2 = wsum[2];
        wsum[0] = 0;
        wsum[1] = s0;
        wsum[2] = s0 + s1;
        wsum[3] = s0 + s1 + s2;
    }
    __syncthreads();
    int o_node = base + wsum[wv] + scan - d;   // absolute segment start
    int node = bu * 256 + t;
    if (node < n) {
        off[node] = o_node;
        endp[node] = o_node + d;
        dinv[node] = rsqrtf((float)d + 1.0f);  // +1 self-loop
    }
    __syncthreads();
    fine[t] = o_node;                          // reuse as cursors
    __syncthreads();
    for (int i = t; i < tot; i += 256) {
        unsigned v = bpk[base + i];
        int pos = atomicAdd(&fine[v & 255], 1);
        srcs[pos] = (int)(v >> 8);
        d8[pos] = (unsigned char)(v & 255u);
    }
}

// ---- h1' = dinv * (BN(x) @ W1) via MFMA bf16. ----
__global__ __launch_bounds__(256) void k_gemm1(
        const float* __restrict__ x, const float* __restrict__ gamma,
        const float* __restrict__ beta, const float* __restrict__ mean,
        const float* __restrict__ var, const float* __restrict__ W1,
        const float* __restrict__ dinv, unsigned* __restrict__ h1u, int n) {
    __shared__ unsigned short xt[64 * 136];     // 64 rows x 272B (pad 8 bf16)
    __shared__ float bs[F_IN], bt[F_IN];
    int t = threadIdx.x;
    if (t < F_IN) {
        float s = rsqrtf(var[t] + BN_EPS) * gamma[t];
        bs[t] = s;
        bt[t] = beta[t] - mean[t] * s;
    }
    int lane = t & 63, wv = t >> 6;
    int quad = lane >> 4, c = lane & 15;
    short8 Bf[4][4];
    #pragma unroll
    for (int nt = 0; nt < 4; ++nt)
        #pragma unroll
        for (int ks = 0; ks < 4; ++ks) {
            short8 v;
            #pragma unroll
            for (int j = 0; j < 8; ++j) {
                int k = ks * 32 + quad * 8 + j;
                __hip_bfloat16 hb = __float2bfloat16(W1[k * F_HID + nt * 16 + c]);
                v[j] = *(short*)&hb;
            }
            Bf[nt][ks] = v;
        }
    __syncthreads();                            // bs/bt ready
    int nb = blockIdx.x * 64;
    #pragma unroll
    for (int it = 0; it < 8; ++it) {
        int i = t + 256 * it;                   // float4 slot: 2048 total
        int node = i >> 5, k4 = i & 31;
        int gn = nb + node;
        float4 v = make_float4(0.f, 0.f, 0.f, 0.f);
        if (gn < n) v = *(const float4*)(x + (size_t)gn * F_IN + k4 * 4);
        float4 sv = *(const float4*)(bs + k4 * 4);
        float4 tv = *(const float4*)(bt + k4 * 4);
        unsigned u0 = pack2(v.x * sv.x + tv.x, v.y * sv.y + tv.y);
        unsigned u1 = pack2(v.z * sv.z + tv.z, v.w * sv.w + tv.w);
        *(uint2*)(xt + node * 136 + k4 * 4) = make_uint2(u0, u1);
    }
    __syncthreads();
    const unsigned short* arow = xt + (wv * 16 + c) * 136;
    f32x4 acc[4] = {f32x4{0.f,0.f,0.f,0.f}, f32x4{0.f,0.f,0.f,0.f},
                    f32x4{0.f,0.f,0.f,0.f}, f32x4{0.f,0.f,0.f,0.f}};
    #pragma unroll
    for (int ks = 0; ks < 4; ++ks) {
        short8 af = *(const short8*)(arow + ks * 32 + quad * 8);  // ds_read_b128
        #pragma unroll
        for (int nt = 0; nt < 4; ++nt)
            acc[nt] = __builtin_amdgcn_mfma_f32_16x16x32_bf16(af, Bf[nt][ks],
                                                              acc[nt], 0, 0, 0);
    }
    size_t R1 = ((size_t)n + 1) * 8;
    #pragma unroll
    for (int r = 0; r < 4; ++r) {
        int node = nb + wv * 16 + quad * 4 + r;
        if (node < n) {
            float d = dinv[node];
            #pragma unroll
            for (int nt = 0; nt < 4; ++nt) {
                __hip_bfloat16 hb = __float2bfloat16(acc[nt][r] * d);
                unsigned short* dst =
                    (unsigned short*)(h1u + (size_t)nt * R1 + (size_t)node * 8) + c;
                *dst = *(unsigned short*)&hb;
            }
        }
    }
}

#define ACC2(p, w) atomicAdd((p), bflo(w)); atomicAdd((p) + 1, bfhi(w));

// ---- conv1: EDGE-PARALLEL gather into LDS accumulators, slice pinned to
//      XCD pair. One block per (bucket=256 nodes, slice=16 feats). Each lane
//      streams a blocked run of edge slots; all gather loads independent
//      (no serial per-node chain); ds_add_f32 into [256][17]-padded acc. ----
__global__ __launch_bounds__(256, 8) void k_conv1(
        const unsigned* __restrict__ h1u, const int* __restrict__ srcs,
        const unsigned char* __restrict__ d8,
        const int* __restrict__ bb, const int* __restrict__ btot,
        const float* __restrict__ dinv, const float* __restrict__ b1,
        unsigned* __restrict__ hus, int n, int NB) {
    __shared__ float acc[256 * 17];
    int bid = blockIdx.x;
    int slice = (bid & 7) >> 1;
    int bu = ((bid >> 3) << 1) | (bid & 1);
    if (bu >= NB) return;
    int t = threadIdx.x;
    #pragma unroll
    for (int i = 0; i < 17; ++i) acc[t + 256 * i] = 0.f;
    __syncthreads();
    const unsigned* base = h1u + (size_t)slice * (((size_t)n + 1) * 8);
    int eb = bb[bu], tot = btot[bu];
    int K = (tot + 255) >> 8;
    int s0 = eb + t * K;
    int s1 = min(s0 + K, eb + tot);
    for (int s = s0; s < s1; ++s) {
        int src = srcs[s];
        int dst = d8[s];
        const unsigned* r = base + (size_t)src * 8;
        uint4 u0 = *(const uint4*)r;
        uint4 u1 = *(const uint4*)(r + 4);
        float* a = acc + dst * 17;
        ACC2(a + 0,  u0.x); ACC2(a + 2,  u0.y);
        ACC2(a + 4,  u0.z); ACC2(a + 6,  u0.w);
        ACC2(a + 8,  u1.x); ACC2(a + 10, u1.y);
        ACC2(a + 12, u1.z); ACC2(a + 14, u1.w);
    }
    __syncthreads();
    int node = bu * 256 + t;
    if (node < n) {
        const float* a = acc + t * 17;
        float d = dinv[node];
        const unsigned* sr = base + (size_t)node * 8;
        uint4 v0 = *(const uint4*)sr;
        uint4 v1 = *(const uint4*)(sr + 4);
        const float* bp = b1 + slice * 16;
        float f[16];
        f[0]  = fmaxf(d * (a[0]  + bflo(v0.x)) + bp[0],  0.f);
        f[1]  = fmaxf(d * (a[1]  + bfhi(v0.x)) + bp[1],  0.f);
        f[2]  = fmaxf(d * (a[2]  + bflo(v0.y)) + bp[2],  0.f);
        f[3]  = fmaxf(d * (a[3]  + bfhi(v0.y)) + bp[3],  0.f);
        f[4]  = fmaxf(d * (a[4]  + bflo(v0.z)) + bp[4],  0.f);
        f[5]  = fmaxf(d * (a[5]  + bfhi(v0.z)) + bp[5],  0.f);
        f[6]  = fmaxf(d * (a[6]  + bflo(v0.w)) + bp[6],  0.f);
        f[7]  = fmaxf(d * (a[7]  + bfhi(v0.w)) + bp[7],  0.f);
        f[8]  = fmaxf(d * (a[8]  + bflo(v1.x)) + bp[8],  0.f);
        f[9]  = fmaxf(d * (a[9]  + bfhi(v1.x)) + bp[9],  0.f);
        f[10] = fmaxf(d * (a[10] + bflo(v1.y)) + bp[10], 0.f);
        f[11] = fmaxf(d * (a[11] + bfhi(v1.y)) + bp[11], 0.f);
        f[12] = fmaxf(d * (a[12] + bflo(v1.z)) + bp[12], 0.f);
        f[13] = fmaxf(d * (a[13] + bfhi(v1.z)) + bp[13], 0.f);
        f[14] = fmaxf(d * (a[14] + bflo(v1.w)) + bp[14], 0.f);
        f[15] = fmaxf(d * (a[15] + bfhi(v1.w)) + bp[15], 0.f);
        uint4* dst = (uint4*)(hus + (size_t)slice * ((size_t)n * 8) +
                              (size_t)node * 8);
        dst[0] = make_uint4(pack2(f[0], f[1]),  pack2(f[2], f[3]),
                            pack2(f[4], f[5]),  pack2(f[6], f[7]));
        dst[1] = make_uint4(pack2(f[8], f[9]),  pack2(f[10], f[11]),
                            pack2(f[12], f[13]), pack2(f[14], f[15]));
    }
}

// ---- h2' = dinv * (h @ W2); output 2 regions, row stride 12 (16B-aligned) ----
__global__ __launch_bounds__(64) void k_gemm2(
        const unsigned* __restrict__ hus, const float* __restrict__ W2,
        const float* __restrict__ dinv, unsigned* __restrict__ h2u, int n) {
    __shared__ float xl[64 * 66];
    int lane = threadIdx.x;
    int nb = blockIdx.x * 64;
    int tn = lane >> 5;
    int q = lane & 31;
    size_t hN = (size_t)n * 8;
    for (int it = 0; it < 32; ++it) {
        int r = it * 2 + tn;
        int node = nb + r;
        unsigned u = 0;
        if (node < n) u = hus[(size_t)(q >> 3) * hN + (long)node * 8 + (q & 7)];
        xl[r * 66 + 2 * q]     = bflo(u);
        xl[r * 66 + 2 * q + 1] = bfhi(u);
    }
    __syncthreads();
    float acc[F_OUT];
    #pragma unroll
    for (int f = 0; f < F_OUT; ++f) acc[f] = 0.f;
    for (int k = 0; k < F_HID; ++k) {
        float xv = xl[lane * 66 + k];
        const float* wr = W2 + k * F_OUT;
        #pragma unroll
        for (int f = 0; f < F_OUT; ++f) acc[f] = fmaf(xv, wr[f], acc[f]);
    }
    int node = nb + lane;
    if (node < n) {
        float d = dinv[node];
        size_t R2 = ((size_t)n + 1) * 12;
        #pragma unroll
        for (int r = 0; r < 2; ++r)
            #pragma unroll
            for (int t = 0; t < 10; ++t)
                h2u[(size_t)r * R2 + (size_t)node * 12 + t] =
                    pack2(acc[r * 20 + 2 * t] * d, acc[r * 20 + 2 * t + 1] * d);
    }
}

// ---- conv2: edge-parallel gather, slice pinned to XCD quad.
//      [256][21]-padded acc (20 feats/slice); 7 blocks/CU (LDS 21.5KB). ----
__global__ __launch_bounds__(256, 7) void k_conv2(
        const unsigned* __restrict__ h2u, const int* __restrict__ srcs,
        const unsigned char* __restrict__ d8,
        const int* __restrict__ bb, const int* __restrict__ btot,
        const float* __restrict__ dinv, const float* __restrict__ b2,
        float* __restrict__ tmp, int n, int NB) {
    __shared__ float acc[256 * 21];
    int bid = blockIdx.x;
    int slice = (bid & 7) >> 2;
    int bu = ((bid >> 3) << 2) | (bid & 3);
    if (bu >= NB) return;
    int t = threadIdx.x;
    #pragma unroll
    for (int i = 0; i < 21; ++i) acc[t + 256 * i] = 0.f;
    __syncthreads();
    const unsigned* base = h2u + (size_t)slice * (((size_t)n + 1) * 12);
    int eb = bb[bu], tot = btot[bu];
    int K = (tot + 255) >> 8;
    int s0 = eb + t * K;
    int s1 = min(s0 + K, eb + tot);
    for (int s = s0; s < s1; ++s) {
        int src = srcs[s];
        int dst = d8[s];
        const unsigned* r = base + (size_t)src * 12;
        uint4 u0 = *(const uint4*)r;
        uint4 u1 = *(const uint4*)(r + 4);
        uint2 u2 = *(const uint2*)(r + 8);
        float* a = acc + dst * 21;
        ACC2(a + 0,  u0.x); ACC2(a + 2,  u0.y);
        ACC2(a + 4,  u0.z); ACC2(a + 6,  u0.w);
        ACC2(a + 8,  u1.x); ACC2(a + 10, u1.y);
        ACC2(a + 12, u1.z); ACC2(a + 14, u1.w);
        ACC2(a + 16, u2.x); ACC2(a + 18, u2.y);
    }
    __syncthreads();
    int node = bu * 256 + t;
    if (node < n) {
        const float* a = acc + t * 21;
        float d = dinv[node];
        const unsigned* sr = base + (size_t)node * 12;
        uint4 v0 = *(const uint4*)sr;
        uint4 v1 = *(const uint4*)(sr + 4);
        uint2 v2 = *(const uint2*)(sr + 8);
        const float* bp = b2 + slice * 20;
        float f[20];
        f[0]  = d * (a[0]  + bflo(v0.x)) + bp[0];
        f[1]  = d * (a[1]  + bfhi(v0.x)) + bp[1];
        f[2]  = d * (a[2]  + bflo(v0.y)) + bp[2];
        f[3]  = d * (a[3]  + bfhi(v0.y)) + bp[3];
        f[4]  = d * (a[4]  + bflo(v0.z)) + bp[4];
        f[5]  = d * (a[5]  + bfhi(v0.z)) + bp[5];
        f[6]  = d * (a[6]  + bflo(v0.w)) + bp[6];
        f[7]  = d * (a[7]  + bfhi(v0.w)) + bp[7];
        f[8]  = d * (a[8]  + bflo(v1.x)) + bp[8];
        f[9]  = d * (a[9]  + bfhi(v1.x)) + bp[9];
        f[10] = d * (a[10] + bflo(v1.y)) + bp[10];
        f[11] = d * (a[11] + bfhi(v1.y)) + bp[11];
        f[12] = d * (a[12] + bflo(v1.z)) + bp[12];
        f[13] = d * (a[13] + bfhi(v1.z)) + bp[13];
        f[14] = d * (a[14] + bflo(v1.w)) + bp[14];
        f[15] = d * (a[15] + bfhi(v1.w)) + bp[15];
        f[16] = d * (a[16] + bflo(v2.x)) + bp[16];
        f[17] = d * (a[17] + bfhi(v2.x)) + bp[17];
        f[18] = d * (a[18] + bflo(v2.y)) + bp[18];
        f[19] = d * (a[19] + bfhi(v2.y)) + bp[19];
        float4* op = (float4*)(tmp + (size_t)node * F_OUT + slice * 20);
        op[0] = make_float4(f[0],  f[1],  f[2],  f[3]);
        op[1] = make_float4(f[4],  f[5],  f[6],  f[7]);
        op[2] = make_float4(f[8],  f[9],  f[10], f[11]);
        op[3] = make_float4(f[12], f[13], f[14], f[15]);
        op[4] = make_float4(f[16], f[17], f[18], f[19]);
    }
}

// ---- log_softmax over the 40 logits of each node; wave per node ----
__global__ __launch_bounds__(256) void k_lsm(const float* __restrict__ tmp,
                                             float* __restrict__ out, int n) {
    int t = blockIdx.x * 256 + threadIdx.x;
    int node = t >> 6, lane = t & 63;
    if (node >= n) return;
    float v = (lane < F_OUT) ? tmp[(long)node * F_OUT + lane] : -INFINITY;
    float m = v;
    #pragma unroll
    for (int o = 32; o > 0; o >>= 1) m = fmaxf(m, __shfl_xor(m, o));
    float ex = (lane < F_OUT) ? expf(v - m) : 0.f;
    float s = ex;
    #pragma unroll
    for (int o = 32; o > 0; o >>= 1) s += __shfl_xor(s, o);
    float lse = logf(s) + m;
    if (lane < F_OUT) out[(long)node * F_OUT + lane] = v - lse;
}

extern "C" void kernel_launch(void* const* d_in, const int* in_sizes, int n_in,
                              void* d_out, int out_size, void* d_ws, size_t ws_size,
                              hipStream_t stream) {
    const float* x     = (const float*)d_in[0];
    const int*   ei    = (const int*)d_in[1];
    const float* gamma = (const float*)d_in[2];
    const float* beta  = (const float*)d_in[3];
    const float* rmean = (const float*)d_in[4];
    const float* rvar  = (const float*)d_in[5];
    const float* W1    = (const float*)d_in[6];
    const float* b1    = (const float*)d_in[7];
    const float* W2    = (const float*)d_in[8];
    const float* b2    = (const float*)d_in[9];
    float* out = (float*)d_out;

    int n = in_sizes[0] / F_IN;
    int E = in_sizes[1] / 2;
    const int* row = ei;       // edge_index[0] = source
    const int* col = ei + E;   // edge_index[1] = target

    // binning geometry: 256 nodes/bucket, <=512 buckets, <=512 edge chunks
    int NB = (n + 255) >> 8;                          // 391 for n=100K
    int chunk = (E + 511) / 512;
    chunk = (chunk + 255) & ~255;
    if (chunk < 256) chunk = 256;
    int nblk = (E + chunk - 1) / chunk;               // <= 512

    int*   off    = (int*)d_ws;                       // n
    int*   endp   = off + n;                          // n
    float* dinv   = (float*)(endp + n);               // n
    int*   cursor = (int*)(dinv + n);                 // 4 ints
    int*   bb     = cursor + 4;                       // 512 bucket bases
    int*   btot   = bb + 512;                         // 512 bucket totals
    int*   bh     = btot + 512;                       // 512*512 cell table
    int*   srcs   = bh + 512 * 512;                   // E ints
    unsigned char* d8 = (unsigned char*)(srcs + E);   // E bytes (dst-in-bucket)
    unsigned* h1u = (unsigned*)(d8 + (((size_t)E + 15) & ~(size_t)15));
    //                                                 4 regions x (n+1)*8 dwords
    unsigned* hu  = h1u + 4 * (((size_t)n + 1) * 8);  // 4 regions x n*8 (slice-major)
    unsigned* h2u = hu + (size_t)n * 32;              // 2 regions x (n+1)*12 dwords
    float* tmp    = (float*)h1u;      // n*40 fp32, aliases dead h1u+hu (post-gemm2)
    unsigned* bpk = hu;               // E dwords, aliases hu (dead until conv1)

    hipMemsetAsync(cursor, 0, 4 * sizeof(int), stream);

    k_hist   <<<nblk, 256, 0, stream>>>(col, E, chunk, nblk, NB, bh);
    k_alloc  <<<NB,   256, 0, stream>>>(bh, bb, btot, cursor, nblk);
    k_scatter<<<nblk, 256, 0, stream>>>(row, col, E, chunk, nblk, NB, bh, bpk);
    k_fine   <<<NB,   256, 0, stream>>>(bpk, bb, btot, off, endp, dinv, srcs, d8, n);

    k_gemm1<<<(n + 63) / 64, 256, 0, stream>>>(x, gamma, beta, rmean, rvar, W1,
                                               dinv, h1u, n);
    // conv1: 4 slices x NB buckets; slice = (bid&7)>>1 (pinned to XCD pair)
    int NBp2 = (NB + 1) & ~1;
    k_conv1<<<4 * NBp2, 256, 0, stream>>>(h1u, srcs, d8, bb, btot, dinv, b1,
                                          hu, n, NB);
    k_gemm2<<<(n + 63) / 64, 64, 0, stream>>>(hu, W2, dinv, h2u, n);
    // conv2: 2 slices x NB buckets; slice = (bid&7)>>2 (pinned to XCD quad)
    int NBp4 = (NB + 3) & ~3;
    k_conv2<<<2 * NBp4, 256, 0, stream>>>(h2u, srcs, d8, bb, btot, dinv, b2,
                                          tmp, n, NB);
    k_lsm  <<<(n + 3) / 4, 256, 0, stream>>>(tmp, out, n);
}

// Round 7
// 329.764 us; speedup vs baseline: 3.8084x; 3.8084x over previous
//
#include <hip/hip_runtime.h>
#include <hip/hip_bf16.h>
#include <math.h>

#define F_IN 128
#define F_HID 64
#define F_OUT 40
#define BN_EPS 1e-5f

typedef __attribute__((ext_vector_type(8))) short short8;
typedef __attribute__((ext_vector_type(4))) float f32x4;

__device__ __forceinline__ float bflo(unsigned u) { return __uint_as_float(u << 16); }
__device__ __forceinline__ float bfhi(unsigned u) { return __uint_as_float(u & 0xffff0000u); }
__device__ __forceinline__ unsigned pack2(float a, float b) {
    __hip_bfloat162 p;
    p.x = __float2bfloat16(a);
    p.y = __float2bfloat16(b);
    return *(unsigned*)&p;
}

// ============ CSR build via 2-level LDS counting sort.
// r1: global atomics write through memory-side at 32B/op -> never on hot path.
// r4: node reordering destroys L2 residency -> natural order everywhere.
// r6: edge-parallel LDS f32 atomics serialize on the LDS atomic pipe (612us,
//     VALU 0.8%) -> keep per-node gather, attack the serial srcs chain instead.

// ---- pass 1: per-(bucket, block) coarse histogram ----
__global__ __launch_bounds__(256) void k_hist(const int* __restrict__ col, int E,
                                              int chunk, int nblk, int NB,
                                              int* __restrict__ bh) {
    __shared__ int hist[512];
    int t = threadIdx.x, blk = blockIdx.x;
    for (int i = t; i < NB; i += 256) hist[i] = 0;
    __syncthreads();
    int e0 = blk * chunk, e1 = min(E, e0 + chunk);
    for (int e = e0 + t; e < e1; e += 256)
        atomicAdd(&hist[col[e] >> 8], 1);
    __syncthreads();
    for (int i = t; i < NB; i += 256)
        bh[(size_t)i * nblk + blk] = hist[i];
}

// ---- pass 2: per-bucket scan of its nblk cells; 1 cursor atomic per bucket. ----
__global__ __launch_bounds__(256) void k_alloc(int* __restrict__ bh,
                                               int* __restrict__ bb,
                                               int* __restrict__ bt,
                                               int* __restrict__ cursor, int nblk) {
    int t = threadIdx.x, bu = blockIdx.x;
    int lane = t & 63, wv = t >> 6;
    size_t base_i = (size_t)bu * nblk;
    int i0 = 2 * t, i1 = 2 * t + 1;
    int a = (i0 < nblk) ? bh[base_i + i0] : 0;
    int b = (i1 < nblk) ? bh[base_i + i1] : 0;
    int p = a + b;
    int scan = p;
    #pragma unroll
    for (int o = 1; o < 64; o <<= 1) {
        int tt = __shfl_up(scan, o);
        if (lane >= o) scan += tt;
    }
    __shared__ int wsum[4];
    if (lane == 63) wsum[wv] = scan;
    __syncthreads();
    if (t == 0) {
        int s0 = wsum[0], s1 = wsum[1], s2 = wsum[2], s3 = wsum[3];
        int total = s0 + s1 + s2 + s3;
        int base = atomicAdd(cursor, total);
        bb[bu] = base;
        bt[bu] = total;
        wsum[0] = base; wsum[1] = base + s0;
        wsum[2] = base + s0 + s1; wsum[3] = base + s0 + s1 + s2;
    }
    __syncthreads();
    int excl = wsum[wv] + scan - p;   // absolute start of cell i0
    if (i0 < nblk) bh[base_i + i0] = excl;
    if (i1 < nblk) bh[base_i + i1] = excl + a;
}

// ---- pass 3: scatter edges into bucket-partitioned order via LDS cursors. ----
__global__ __launch_bounds__(256) void k_scatter(const int* __restrict__ row,
                                                 const int* __restrict__ col,
                                                 int E, int chunk, int nblk, int NB,
                                                 const int* __restrict__ bh,
                                                 unsigned* __restrict__ bpk) {
    __shared__ int cur[512];
    int t = threadIdx.x, blk = blockIdx.x;
    for (int i = t; i < NB; i += 256) cur[i] = bh[(size_t)i * nblk + blk];
    __syncthreads();
    int e0 = blk * chunk, e1 = min(E, e0 + chunk);
    for (int e = e0 + t; e < e1; e += 256) {
        int c = col[e];
        int pos = atomicAdd(&cur[c >> 8], 1);
        bpk[pos] = ((unsigned)row[e] << 8) | (unsigned)(c & 255);
    }
}

// ---- pass 4: per-bucket fine histogram + scan -> off/endp/dinv; place srcs. ----
__global__ __launch_bounds__(256) void k_fine(const unsigned* __restrict__ bpk,
                                              const int* __restrict__ bb,
                                              const int* __restrict__ bt,
                                              int* __restrict__ off,
                                              int* __restrict__ endp,
                                              float* __restrict__ dinv,
                                              int* __restrict__ srcs, int n) {
    __shared__ int fine[256];
    __shared__ int wsum[4];
    int t = threadIdx.x, bu = blockIdx.x;
    int lane = t & 63, wv = t >> 6;
    fine[t] = 0;
    __syncthreads();
    int base = bb[bu], tot = bt[bu];
    for (int i = t; i < tot; i += 256)
        atomicAdd(&fine[bpk[base + i] & 255], 1);
    __syncthreads();
    int d = fine[t];
    int scan = d;
    #pragma unroll
    for (int o = 1; o < 64; o <<= 1) {
        int tt = __shfl_up(scan, o);
        if (lane >= o) scan += tt;
    }
    if (lane == 63) wsum[wv] = scan;
    __syncthreads();
    if (t == 0) {
        int s0 = wsum[0], s1 = wsum[1], s2 = wsum[2];
        wsum[0] = 0;
        wsum[1] = s0;
        wsum[2] = s0 + s1;
        wsum[3] = s0 + s1 + s2;
    }
    __syncthreads();
    int o_node = base + wsum[wv] + scan - d;   // absolute segment start
    int node = bu * 256 + t;
    if (node < n) {
        off[node] = o_node;
        endp[node] = o_node + d;
        dinv[node] = rsqrtf((float)d + 1.0f);  // +1 self-loop
    }
    __syncthreads();
    fine[t] = o_node;                          // reuse as cursors
    __syncthreads();
    for (int i = t; i < tot; i += 256) {
        unsigned v = bpk[base + i];
        int pos = atomicAdd(&fine[v & 255], 1);
        srcs[pos] = (int)(v >> 8);
    }
}

// ---- h1' = dinv * (BN(x) @ W1) via MFMA bf16. Block 0 also zeroes the
//      h1u/h2u pad rows (row n) consumed by idle gather lanes (was k_zero). ----
__global__ __launch_bounds__(256) void k_gemm1(
        const float* __restrict__ x, const float* __restrict__ gamma,
        const float* __restrict__ beta, const float* __restrict__ mean,
        const float* __restrict__ var, const float* __restrict__ W1,
        const float* __restrict__ dinv, unsigned* __restrict__ h1u,
        unsigned* __restrict__ h2u, int n) {
    __shared__ unsigned short xt[64 * 136];     // 64 rows x 272B (pad 8 bf16)
    __shared__ float bs[F_IN], bt[F_IN];
    int t = threadIdx.x;
    if (blockIdx.x == 0) {
        size_t R1 = ((size_t)n + 1) * 8;
        size_t R2 = ((size_t)n + 1) * 10;
        if (t < 32) h1u[(size_t)(t >> 3) * R1 + (size_t)n * 8 + (t & 7)] = 0u;
        if (t >= 32 && t < 52) {
            int q = t - 32;
            h2u[(size_t)(q / 10) * R2 + (size_t)n * 10 + (q % 10)] = 0u;
        }
    }
    if (t < F_IN) {
        float s = rsqrtf(var[t] + BN_EPS) * gamma[t];
        bs[t] = s;
        bt[t] = beta[t] - mean[t] * s;
    }
    int lane = t & 63, wv = t >> 6;
    int quad = lane >> 4, c = lane & 15;
    short8 Bf[4][4];
    #pragma unroll
    for (int nt = 0; nt < 4; ++nt)
        #pragma unroll
        for (int ks = 0; ks < 4; ++ks) {
            short8 v;
            #pragma unroll
            for (int j = 0; j < 8; ++j) {
                int k = ks * 32 + quad * 8 + j;
                __hip_bfloat16 hb = __float2bfloat16(W1[k * F_HID + nt * 16 + c]);
                v[j] = *(short*)&hb;
            }
            Bf[nt][ks] = v;
        }
    __syncthreads();                            // bs/bt ready
    int nb = blockIdx.x * 64;
    #pragma unroll
    for (int it = 0; it < 8; ++it) {
        int i = t + 256 * it;                   // float4 slot: 2048 total
        int node = i >> 5, k4 = i & 31;
        int gn = nb + node;
        float4 v = make_float4(0.f, 0.f, 0.f, 0.f);
        if (gn < n) v = *(const float4*)(x + (size_t)gn * F_IN + k4 * 4);
        float4 sv = *(const float4*)(bs + k4 * 4);
        float4 tv = *(const float4*)(bt + k4 * 4);
        unsigned u0 = pack2(v.x * sv.x + tv.x, v.y * sv.y + tv.y);
        unsigned u1 = pack2(v.z * sv.z + tv.z, v.w * sv.w + tv.w);
        *(uint2*)(xt + node * 136 + k4 * 4) = make_uint2(u0, u1);
    }
    __syncthreads();
    const unsigned short* arow = xt + (wv * 16 + c) * 136;
    f32x4 acc[4] = {f32x4{0.f,0.f,0.f,0.f}, f32x4{0.f,0.f,0.f,0.f},
                    f32x4{0.f,0.f,0.f,0.f}, f32x4{0.f,0.f,0.f,0.f}};
    #pragma unroll
    for (int ks = 0; ks < 4; ++ks) {
        short8 af = *(const short8*)(arow + ks * 32 + quad * 8);  // ds_read_b128
        #pragma unroll
        for (int nt = 0; nt < 4; ++nt)
            acc[nt] = __builtin_amdgcn_mfma_f32_16x16x32_bf16(af, Bf[nt][ks],
                                                              acc[nt], 0, 0, 0);
    }
    size_t R1 = ((size_t)n + 1) * 8;
    #pragma unroll
    for (int r = 0; r < 4; ++r) {
        int node = nb + wv * 16 + quad * 4 + r;
        if (node < n) {
            float d = dinv[node];
            #pragma unroll
            for (int nt = 0; nt < 4; ++nt) {
                __hip_bfloat16 hb = __float2bfloat16(acc[nt][r] * d);
                unsigned short* dst =
                    (unsigned short*)(h1u + (size_t)nt * R1 + (size_t)node * 8) + c;
                *dst = *(unsigned short*)&hb;
            }
        }
    }
}

// ---- conv1: natural-order gather, slice pinned to XCD pair.
//      8 lanes/node, 4-BATCH UNROLL: all 4 srcs loads (32 edge slots) issue
//      together, then 32 independent gathers -- one latency round per node
//      instead of ~3.5 serial batch rounds (r6 post-mortem: the ~600cy L3
//      srcs load headed every batch's serial chain). Edge order preserved. ----
__global__ __launch_bounds__(256, 8) void k_conv1(
        const unsigned* __restrict__ h1u, const int* __restrict__ srcs,
        const int* __restrict__ off, const int* __restrict__ endp,
        const float* __restrict__ dinv, const float* __restrict__ b1,
        unsigned* __restrict__ hus, int n, int nb1) {
    int bid = blockIdx.x;
    int slice = (bid & 7) >> 1;
    int idx = ((bid >> 3) << 1) | (bid & 1);
    if (idx >= nb1) return;
    int lane = threadIdx.x & 63;
    int g = lane >> 3, f = lane & 7, gb = g * 8;
    const unsigned* base = h1u + (size_t)slice * (((size_t)n + 1) * 8);
    int node = idx * 32 + (threadIdx.x >> 6) * 8 + g;
    int nodec = (node < n) ? node : n;
    int j = (node < n) ? off[node] : 0;
    int e = (node < n) ? endp[node] : 0;
    float a0 = 0.f, a1 = 0.f;
    while (__any(j < e)) {
        int sv0 = (j +      f < e) ? srcs[j + f]      : n;
        int sv1 = (j + 8  + f < e) ? srcs[j + 8 + f]  : n;
        int sv2 = (j + 16 + f < e) ? srcs[j + 16 + f] : n;
        int sv3 = (j + 24 + f < e) ? srcs[j + 24 + f] : n;
        #pragma unroll
        for (int k = 0; k < 8; ++k) {
            int s = __shfl(sv0, gb + k);
            unsigned u = base[(size_t)s * 8 + f];
            a0 += bflo(u); a1 += bfhi(u);
        }
        #pragma unroll
        for (int k = 0; k < 8; ++k) {
            int s = __shfl(sv1, gb + k);
            unsigned u = base[(size_t)s * 8 + f];
            a0 += bflo(u); a1 += bfhi(u);
        }
        #pragma unroll
        for (int k = 0; k < 8; ++k) {
            int s = __shfl(sv2, gb + k);
            unsigned u = base[(size_t)s * 8 + f];
            a0 += bflo(u); a1 += bfhi(u);
        }
        #pragma unroll
        for (int k = 0; k < 8; ++k) {
            int s = __shfl(sv3, gb + k);
            unsigned u = base[(size_t)s * 8 + f];
            a0 += bflo(u); a1 += bfhi(u);
        }
        j += 32;
    }
    unsigned us = base[(size_t)nodec * 8 + f];
    float d = (node < n) ? dinv[node] : 0.f;
    float2 bb = ((const float2*)b1)[slice * 8 + f];
    float h0 = fmaxf(d * (a0 + bflo(us)) + bb.x, 0.f);
    float h1 = fmaxf(d * (a1 + bfhi(us)) + bb.y, 0.f);
    if (node < n)
        hus[(size_t)slice * ((size_t)n * 8) + (size_t)node * 8 + f] = pack2(h0, h1);
}

// ---- h2' = dinv * (h @ W2); h read from slice-major hu regions ----
__global__ __launch_bounds__(64) void k_gemm2(
        const unsigned* __restrict__ hus, const float* __restrict__ W2,
        const float* __restrict__ dinv, unsigned* __restrict__ h2u, int n) {
    __shared__ float xl[64 * 66];
    int lane = threadIdx.x;
    int nb = blockIdx.x * 64;
    int tn = lane >> 5;
    int q = lane & 31;
    size_t hN = (size_t)n * 8;
    for (int it = 0; it < 32; ++it) {
        int r = it * 2 + tn;
        int node = nb + r;
        unsigned u = 0;
        if (node < n) u = hus[(size_t)(q >> 3) * hN + (long)node * 8 + (q & 7)];
        xl[r * 66 + 2 * q]     = bflo(u);
        xl[r * 66 + 2 * q + 1] = bfhi(u);
    }
    __syncthreads();
    float acc[F_OUT];
    #pragma unroll
    for (int f = 0; f < F_OUT; ++f) acc[f] = 0.f;
    for (int k = 0; k < F_HID; ++k) {
        float xv = xl[lane * 66 + k];
        const float* wr = W2 + k * F_OUT;
        #pragma unroll
        for (int f = 0; f < F_OUT; ++f) acc[f] = fmaf(xv, wr[f], acc[f]);
    }
    int node = nb + lane;
    if (node < n) {
        float d = dinv[node];
        size_t R2 = ((size_t)n + 1) * 10;
        #pragma unroll
        for (int r = 0; r < 2; ++r)
            #pragma unroll
            for (int t = 0; t < 10; ++t)
                h2u[(size_t)r * R2 + (long)node * 10 + t] =
                    pack2(acc[r * 20 + 2 * t] * d, acc[r * 20 + 2 * t + 1] * d);
    }
}

// ---- conv2: natural-order gather, slice pinned to XCD quad.
//      10 lanes/node (6 groups/wave), 3-BATCH UNROLL (30 edge slots). ----
__global__ __launch_bounds__(256, 8) void k_conv2(
        const unsigned* __restrict__ h2u, const int* __restrict__ srcs,
        const int* __restrict__ off, const int* __restrict__ endp,
        const float* __restrict__ dinv, const float* __restrict__ b2,
        float* __restrict__ tmp, int n, int nb2) {
    int bid = blockIdx.x;
    int slice = (bid & 7) >> 2;
    int idx = ((bid >> 3) << 2) | (bid & 3);
    if (idx >= nb2) return;
    int lane = threadIdx.x & 63;
    bool lact = lane < 60;
    int g = lane / 10; if (g > 5) g = 5;
    int f = lane % 10;
    int gb = g * 10;
    const unsigned* base = h2u + (size_t)slice * (((size_t)n + 1) * 10);
    int node = idx * 24 + (threadIdx.x >> 6) * 6 + g;
    if (!lact) node = n;
    int nodec = (node < n) ? node : n;
    int j = (node < n) ? off[node] : 0;
    int e = (node < n) ? endp[node] : 0;
    float a0 = 0.f, a1 = 0.f;
    while (__any(j < e)) {
        int sv0 = (j +      f < e) ? srcs[j + f]      : n;
        int sv1 = (j + 10 + f < e) ? srcs[j + 10 + f] : n;
        int sv2 = (j + 20 + f < e) ? srcs[j + 20 + f] : n;
        #pragma unroll
        for (int k = 0; k < 10; ++k) {
            int s = __shfl(sv0, gb + k);
            unsigned u = base[(size_t)s * 10 + f];
            a0 += bflo(u); a1 += bfhi(u);
        }
        #pragma unroll
        for (int k = 0; k < 10; ++k) {
            int s = __shfl(sv1, gb + k);
            unsigned u = base[(size_t)s * 10 + f];
            a0 += bflo(u); a1 += bfhi(u);
        }
        #pragma unroll
        for (int k = 0; k < 10; ++k) {
            int s = __shfl(sv2, gb + k);
            unsigned u = base[(size_t)s * 10 + f];
            a0 += bflo(u); a1 += bfhi(u);
        }
        j += 30;
    }
    unsigned us = base[(size_t)nodec * 10 + f];
    float d = (node < n) ? dinv[node] : 0.f;
    float2 bb = ((const float2*)b2)[slice * 10 + f];
    float v0 = d * (a0 + bflo(us)) + bb.x;
    float v1 = d * (a1 + bfhi(us)) + bb.y;
    if (node < n && lact) {
        float2 o;
        o.x = v0; o.y = v1;
        *(float2*)(tmp + (long)node * F_OUT + slice * 20 + 2 * f) = o;
    }
}

// ---- log_softmax over the 40 logits of each node; wave per node ----
__global__ __launch_bounds__(256) void k_lsm(const float* __restrict__ tmp,
                                             float* __restrict__ out, int n) {
    int t = blockIdx.x * 256 + threadIdx.x;
    int node = t >> 6, lane = t & 63;
    if (node >= n) return;
    float v = (lane < F_OUT) ? tmp[(long)node * F_OUT + lane] : -INFINITY;
    float m = v;
    #pragma unroll
    for (int o = 32; o > 0; o >>= 1) m = fmaxf(m, __shfl_xor(m, o));
    float ex = (lane < F_OUT) ? expf(v - m) : 0.f;
    float s = ex;
    #pragma unroll
    for (int o = 32; o > 0; o >>= 1) s += __shfl_xor(s, o);
    float lse = logf(s) + m;
    if (lane < F_OUT) out[(long)node * F_OUT + lane] = v - lse;
}

extern "C" void kernel_launch(void* const* d_in, const int* in_sizes, int n_in,
                              void* d_out, int out_size, void* d_ws, size_t ws_size,
                              hipStream_t stream) {
    const float* x     = (const float*)d_in[0];
    const int*   ei    = (const int*)d_in[1];
    const float* gamma = (const float*)d_in[2];
    const float* beta  = (const float*)d_in[3];
    const float* rmean = (const float*)d_in[4];
    const float* rvar  = (const float*)d_in[5];
    const float* W1    = (const float*)d_in[6];
    const float* b1    = (const float*)d_in[7];
    const float* W2    = (const float*)d_in[8];
    const float* b2    = (const float*)d_in[9];
    float* out = (float*)d_out;

    int n = in_sizes[0] / F_IN;
    int E = in_sizes[1] / 2;
    const int* row = ei;       // edge_index[0] = source
    const int* col = ei + E;   // edge_index[1] = target

    // binning geometry: 256 nodes/bucket, <=512 buckets, <=512 edge chunks
    int NB = (n + 255) >> 8;                          // 391 for n=100K
    int chunk = (E + 511) / 512;
    chunk = (chunk + 255) & ~255;
    if (chunk < 256) chunk = 256;
    int nblk = (E + chunk - 1) / chunk;               // <= 512

    int*   off    = (int*)d_ws;                       // n
    int*   endp   = off + n;                          // n
    float* dinv   = (float*)(endp + n);               // n
    int*   cursor = (int*)(dinv + n);                 // 4 ints
    int*   bb     = cursor + 4;                       // 512 bucket bases
    int*   btot   = bb + 512;                         // 512 bucket totals
    int*   bh     = btot + 512;                       // 512*512 cell table
    int*   srcs   = bh + 512 * 512;                   // E ints
    unsigned* h1u = (unsigned*)(srcs + E);            // 4 regions x (n+1)*8 dwords
    unsigned* hu  = h1u + 4 * (((size_t)n + 1) * 8);  // 4 regions x n*8 (slice-major)
    unsigned* h2u = hu + (size_t)n * 32;              // 2 regions x (n+1)*10 dwords
    float* tmp    = (float*)h1u;      // n*40 fp32, aliases dead h1u (post-conv1)
    unsigned* bpk = hu;               // E dwords, aliases hu (dead until conv1)

    hipMemsetAsync(cursor, 0, 4 * sizeof(int), stream);

    k_hist   <<<nblk, 256, 0, stream>>>(col, E, chunk, nblk, NB, bh);
    k_alloc  <<<NB,   256, 0, stream>>>(bh, bb, btot, cursor, nblk);
    k_scatter<<<nblk, 256, 0, stream>>>(row, col, E, chunk, nblk, NB, bh, bpk);
    k_fine   <<<NB,   256, 0, stream>>>(bpk, bb, btot, off, endp, dinv, srcs, n);

    k_gemm1<<<(n + 63) / 64, 256, 0, stream>>>(x, gamma, beta, rmean, rvar, W1,
                                               dinv, h1u, h2u, n);
    // conv1: 4 slices x nb1 node-blocks (32 nodes each); slice = (bid&7)>>1
    int nb1 = (n + 31) / 32;
    int nb1p = (nb1 + 1) & ~1;                        // even -> grid % 8 == 0
    k_conv1<<<4 * nb1p, 256, 0, stream>>>(h1u, srcs, off, endp, dinv, b1,
                                          hu, n, nb1);
    k_gemm2<<<(n + 63) / 64, 64, 0, stream>>>(hu, W2, dinv, h2u, n);
    // conv2: 2 slices x nb2 node-blocks (24 nodes each); slice = (bid&7)>>2
    int nb2 = (n + 23) / 24;
    int nb2p = (nb2 + 3) & ~3;                        // mult of 4 -> grid % 8 == 0
    k_conv2<<<2 * nb2p, 256, 0, stream>>>(h2u, srcs, off, endp, dinv, b2,
                                          tmp, n, nb2);
    k_lsm  <<<(n + 3) / 4, 256, 0, stream>>>(tmp, out, n);
}

// Round 8
// 326.341 us; speedup vs baseline: 3.8483x; 1.0105x over previous
//
#include <hip/hip_runtime.h>
#include <hip/hip_bf16.h>
#include <math.h>

#define F_IN 128
#define F_HID 64
#define F_OUT 40
#define BN_EPS 1e-5f

typedef __attribute__((ext_vector_type(8))) short short8;
typedef __attribute__((ext_vector_type(4))) float f32x4;

__device__ __forceinline__ float bflo(unsigned u) { return __uint_as_float(u << 16); }
__device__ __forceinline__ float bfhi(unsigned u) { return __uint_as_float(u & 0xffff0000u); }
__device__ __forceinline__ unsigned pack2(float a, float b) {
    __hip_bfloat162 p;
    p.x = __float2bfloat16(a);
    p.y = __float2bfloat16(b);
    return *(unsigned*)&p;
}

// ============ CSR build via 2-level LDS counting sort.
// r1: global atomics write through memory-side at 32B/op -> never on hot path.
// r4: node reordering destroys L2 residency -> natural order everywhere.
// r6: edge-parallel LDS f32 atomics serialize on the LDS atomic pipe.
// r7: 2-slice conv2 (4.0MB region == per-XCD L2) thrashed under unroll
//     (FETCH 157MB, 49% BW) -> gather region must be << 4MB: conv2 now
//     4 slices x 10 feats (2.0MB region), like conv1's 3.2MB (which held).

// ---- pass 1: per-(bucket, block) coarse histogram ----
__global__ __launch_bounds__(256) void k_hist(const int* __restrict__ col, int E,
                                              int chunk, int nblk, int NB,
                                              int* __restrict__ bh) {
    __shared__ int hist[512];
    int t = threadIdx.x, blk = blockIdx.x;
    for (int i = t; i < NB; i += 256) hist[i] = 0;
    __syncthreads();
    int e0 = blk * chunk, e1 = min(E, e0 + chunk);
    for (int e = e0 + t; e < e1; e += 256)
        atomicAdd(&hist[col[e] >> 8], 1);
    __syncthreads();
    for (int i = t; i < NB; i += 256)
        bh[(size_t)i * nblk + blk] = hist[i];
}

// ---- pass 2: per-bucket scan of its nblk cells; 1 cursor atomic per bucket. ----
__global__ __launch_bounds__(256) void k_alloc(int* __restrict__ bh,
                                               int* __restrict__ bb,
                                               int* __restrict__ bt,
                                               int* __restrict__ cursor, int nblk) {
    int t = threadIdx.x, bu = blockIdx.x;
    int lane = t & 63, wv = t >> 6;
    size_t base_i = (size_t)bu * nblk;
    int i0 = 2 * t, i1 = 2 * t + 1;
    int a = (i0 < nblk) ? bh[base_i + i0] : 0;
    int b = (i1 < nblk) ? bh[base_i + i1] : 0;
    int p = a + b;
    int scan = p;
    #pragma unroll
    for (int o = 1; o < 64; o <<= 1) {
        int tt = __shfl_up(scan, o);
        if (lane >= o) scan += tt;
    }
    __shared__ int wsum[4];
    if (lane == 63) wsum[wv] = scan;
    __syncthreads();
    if (t == 0) {
        int s0 = wsum[0], s1 = wsum[1], s2 = wsum[2], s3 = wsum[3];
        int total = s0 + s1 + s2 + s3;
        int base = atomicAdd(cursor, total);
        bb[bu] = base;
        bt[bu] = total;
        wsum[0] = base; wsum[1] = base + s0;
        wsum[2] = base + s0 + s1; wsum[3] = base + s0 + s1 + s2;
    }
    __syncthreads();
    int excl = wsum[wv] + scan - p;   // absolute start of cell i0
    if (i0 < nblk) bh[base_i + i0] = excl;
    if (i1 < nblk) bh[base_i + i1] = excl + a;
}

// ---- pass 3: scatter edges into bucket-partitioned order via LDS cursors. ----
__global__ __launch_bounds__(256) void k_scatter(const int* __restrict__ row,
                                                 const int* __restrict__ col,
                                                 int E, int chunk, int nblk, int NB,
                                                 const int* __restrict__ bh,
                                                 unsigned* __restrict__ bpk) {
    __shared__ int cur[512];
    int t = threadIdx.x, blk = blockIdx.x;
    for (int i = t; i < NB; i += 256) cur[i] = bh[(size_t)i * nblk + blk];
    __syncthreads();
    int e0 = blk * chunk, e1 = min(E, e0 + chunk);
    for (int e = e0 + t; e < e1; e += 256) {
        int c = col[e];
        int pos = atomicAdd(&cur[c >> 8], 1);
        bpk[pos] = ((unsigned)row[e] << 8) | (unsigned)(c & 255);
    }
}

// ---- pass 4: per-bucket fine histogram + scan -> off/endp/dinv; place srcs. ----
__global__ __launch_bounds__(256) void k_fine(const unsigned* __restrict__ bpk,
                                              const int* __restrict__ bb,
                                              const int* __restrict__ bt,
                                              int* __restrict__ off,
                                              int* __restrict__ endp,
                                              float* __restrict__ dinv,
                                              int* __restrict__ srcs, int n) {
    __shared__ int fine[256];
    __shared__ int wsum[4];
    int t = threadIdx.x, bu = blockIdx.x;
    int lane = t & 63, wv = t >> 6;
    fine[t] = 0;
    __syncthreads();
    int base = bb[bu], tot = bt[bu];
    for (int i = t; i < tot; i += 256)
        atomicAdd(&fine[bpk[base + i] & 255], 1);
    __syncthreads();
    int d = fine[t];
    int scan = d;
    #pragma unroll
    for (int o = 1; o < 64; o <<= 1) {
        int tt = __shfl_up(scan, o);
        if (lane >= o) scan += tt;
    }
    if (lane == 63) wsum[wv] = scan;
    __syncthreads();
    if (t == 0) {
        int s0 = wsum[0], s1 = wsum[1], s2 = wsum[2];
        wsum[0] = 0;
        wsum[1] = s0;
        wsum[2] = s0 + s1;
        wsum[3] = s0 + s1 + s2;
    }
    __syncthreads();
    int o_node = base + wsum[wv] + scan - d;   // absolute segment start
    int node = bu * 256 + t;
    if (node < n) {
        off[node] = o_node;
        endp[node] = o_node + d;
        dinv[node] = rsqrtf((float)d + 1.0f);  // +1 self-loop
    }
    __syncthreads();
    fine[t] = o_node;                          // reuse as cursors
    __syncthreads();
    for (int i = t; i < tot; i += 256) {
        unsigned v = bpk[base + i];
        int pos = atomicAdd(&fine[v & 255], 1);
        srcs[pos] = (int)(v >> 8);
    }
}

// ---- h1' = dinv * (BN(x) @ W1) via MFMA bf16. Block 0 also zeroes the
//      h1u/h2u pad rows (row n) consumed by idle gather lanes. ----
__global__ __launch_bounds__(256) void k_gemm1(
        const float* __restrict__ x, const float* __restrict__ gamma,
        const float* __restrict__ beta, const float* __restrict__ mean,
        const float* __restrict__ var, const float* __restrict__ W1,
        const float* __restrict__ dinv, unsigned* __restrict__ h1u,
        unsigned* __restrict__ h2u, int n) {
    __shared__ unsigned short xt[64 * 136];     // 64 rows x 272B (pad 8 bf16)
    __shared__ float bs[F_IN], bt[F_IN];
    int t = threadIdx.x;
    if (blockIdx.x == 0) {
        size_t R1 = ((size_t)n + 1) * 8;
        size_t R2 = ((size_t)n + 1) * 5;
        if (t < 32) h1u[(size_t)(t >> 3) * R1 + (size_t)n * 8 + (t & 7)] = 0u;
        if (t >= 32 && t < 52) {
            int q = t - 32;
            h2u[(size_t)(q / 5) * R2 + (size_t)n * 5 + (q % 5)] = 0u;
        }
    }
    if (t < F_IN) {
        float s = rsqrtf(var[t] + BN_EPS) * gamma[t];
        bs[t] = s;
        bt[t] = beta[t] - mean[t] * s;
    }
    int lane = t & 63, wv = t >> 6;
    int quad = lane >> 4, c = lane & 15;
    short8 Bf[4][4];
    #pragma unroll
    for (int nt = 0; nt < 4; ++nt)
        #pragma unroll
        for (int ks = 0; ks < 4; ++ks) {
            short8 v;
            #pragma unroll
            for (int j = 0; j < 8; ++j) {
                int k = ks * 32 + quad * 8 + j;
                __hip_bfloat16 hb = __float2bfloat16(W1[k * F_HID + nt * 16 + c]);
                v[j] = *(short*)&hb;
            }
            Bf[nt][ks] = v;
        }
    __syncthreads();                            // bs/bt ready
    int nb = blockIdx.x * 64;
    #pragma unroll
    for (int it = 0; it < 8; ++it) {
        int i = t + 256 * it;                   // float4 slot: 2048 total
        int node = i >> 5, k4 = i & 31;
        int gn = nb + node;
        float4 v = make_float4(0.f, 0.f, 0.f, 0.f);
        if (gn < n) v = *(const float4*)(x + (size_t)gn * F_IN + k4 * 4);
        float4 sv = *(const float4*)(bs + k4 * 4);
        float4 tv = *(const float4*)(bt + k4 * 4);
        unsigned u0 = pack2(v.x * sv.x + tv.x, v.y * sv.y + tv.y);
        unsigned u1 = pack2(v.z * sv.z + tv.z, v.w * sv.w + tv.w);
        *(uint2*)(xt + node * 136 + k4 * 4) = make_uint2(u0, u1);
    }
    __syncthreads();
    const unsigned short* arow = xt + (wv * 16 + c) * 136;
    f32x4 acc[4] = {f32x4{0.f,0.f,0.f,0.f}, f32x4{0.f,0.f,0.f,0.f},
                    f32x4{0.f,0.f,0.f,0.f}, f32x4{0.f,0.f,0.f,0.f}};
    #pragma unroll
    for (int ks = 0; ks < 4; ++ks) {
        short8 af = *(const short8*)(arow + ks * 32 + quad * 8);  // ds_read_b128
        #pragma unroll
        for (int nt = 0; nt < 4; ++nt)
            acc[nt] = __builtin_amdgcn_mfma_f32_16x16x32_bf16(af, Bf[nt][ks],
                                                              acc[nt], 0, 0, 0);
    }
    size_t R1 = ((size_t)n + 1) * 8;
    #pragma unroll
    for (int r = 0; r < 4; ++r) {
        int node = nb + wv * 16 + quad * 4 + r;
        if (node < n) {
            float d = dinv[node];
            #pragma unroll
            for (int nt = 0; nt < 4; ++nt) {
                __hip_bfloat16 hb = __float2bfloat16(acc[nt][r] * d);
                unsigned short* dst =
                    (unsigned short*)(h1u + (size_t)nt * R1 + (size_t)node * 8) + c;
                *dst = *(unsigned short*)&hb;
            }
        }
    }
}

// ---- conv1: natural-order gather, slice pinned to XCD pair (3.2MB region,
//      L2-resident). 8 lanes/node, 4-batch unroll (one latency round/node). ----
__global__ __launch_bounds__(256, 8) void k_conv1(
        const unsigned* __restrict__ h1u, const int* __restrict__ srcs,
        const int* __restrict__ off, const int* __restrict__ endp,
        const float* __restrict__ dinv, const float* __restrict__ b1,
        unsigned* __restrict__ hus, int n, int nb1) {
    int bid = blockIdx.x;
    int slice = (bid & 7) >> 1;
    int idx = ((bid >> 3) << 1) | (bid & 1);
    if (idx >= nb1) return;
    int lane = threadIdx.x & 63;
    int g = lane >> 3, f = lane & 7, gb = g * 8;
    const unsigned* base = h1u + (size_t)slice * (((size_t)n + 1) * 8);
    int node = idx * 32 + (threadIdx.x >> 6) * 8 + g;
    int nodec = (node < n) ? node : n;
    int j = (node < n) ? off[node] : 0;
    int e = (node < n) ? endp[node] : 0;
    float a0 = 0.f, a1 = 0.f;
    while (__any(j < e)) {
        int sv0 = (j +      f < e) ? srcs[j + f]      : n;
        int sv1 = (j + 8  + f < e) ? srcs[j + 8 + f]  : n;
        int sv2 = (j + 16 + f < e) ? srcs[j + 16 + f] : n;
        int sv3 = (j + 24 + f < e) ? srcs[j + 24 + f] : n;
        #pragma unroll
        for (int k = 0; k < 8; ++k) {
            int s = __shfl(sv0, gb + k);
            unsigned u = base[(size_t)s * 8 + f];
            a0 += bflo(u); a1 += bfhi(u);
        }
        #pragma unroll
        for (int k = 0; k < 8; ++k) {
            int s = __shfl(sv1, gb + k);
            unsigned u = base[(size_t)s * 8 + f];
            a0 += bflo(u); a1 += bfhi(u);
        }
        #pragma unroll
        for (int k = 0; k < 8; ++k) {
            int s = __shfl(sv2, gb + k);
            unsigned u = base[(size_t)s * 8 + f];
            a0 += bflo(u); a1 += bfhi(u);
        }
        #pragma unroll
        for (int k = 0; k < 8; ++k) {
            int s = __shfl(sv3, gb + k);
            unsigned u = base[(size_t)s * 8 + f];
            a0 += bflo(u); a1 += bfhi(u);
        }
        j += 32;
    }
    unsigned us = base[(size_t)nodec * 8 + f];
    float d = (node < n) ? dinv[node] : 0.f;
    float2 bb = ((const float2*)b1)[slice * 8 + f];
    float h0 = fmaxf(d * (a0 + bflo(us)) + bb.x, 0.f);
    float h1 = fmaxf(d * (a1 + bfhi(us)) + bb.y, 0.f);
    if (node < n)
        hus[(size_t)slice * ((size_t)n * 8) + (size_t)node * 8 + f] = pack2(h0, h1);
}

// ---- h2' = dinv * (h @ W2); output 4 slice-regions of 10 feats
//      (5 packed dwords/row, region 2.0MB -> L2-resident in conv2) ----
__global__ __launch_bounds__(64) void k_gemm2(
        const unsigned* __restrict__ hus, const float* __restrict__ W2,
        const float* __restrict__ dinv, unsigned* __restrict__ h2u, int n) {
    __shared__ float xl[64 * 66];
    int lane = threadIdx.x;
    int nb = blockIdx.x * 64;
    int tn = lane >> 5;
    int q = lane & 31;
    size_t hN = (size_t)n * 8;
    for (int it = 0; it < 32; ++it) {
        int r = it * 2 + tn;
        int node = nb + r;
        unsigned u = 0;
        if (node < n) u = hus[(size_t)(q >> 3) * hN + (long)node * 8 + (q & 7)];
        xl[r * 66 + 2 * q]     = bflo(u);
        xl[r * 66 + 2 * q + 1] = bfhi(u);
    }
    __syncthreads();
    float acc[F_OUT];
    #pragma unroll
    for (int f = 0; f < F_OUT; ++f) acc[f] = 0.f;
    for (int k = 0; k < F_HID; ++k) {
        float xv = xl[lane * 66 + k];
        const float* wr = W2 + k * F_OUT;
        #pragma unroll
        for (int f = 0; f < F_OUT; ++f) acc[f] = fmaf(xv, wr[f], acc[f]);
    }
    int node = nb + lane;
    if (node < n) {
        float d = dinv[node];
        size_t R2 = ((size_t)n + 1) * 5;
        #pragma unroll
        for (int r = 0; r < 4; ++r)
            #pragma unroll
            for (int t = 0; t < 5; ++t)
                h2u[(size_t)r * R2 + (size_t)node * 5 + t] =
                    pack2(acc[r * 10 + 2 * t] * d, acc[r * 10 + 2 * t + 1] * d);
    }
}

// ---- conv2: 4 slices x 10 feats, slice pinned to XCD pair (2.0MB region).
//      5 lanes/node (12 groups/wave), 4-batch unroll (20 slots).
//      Output tmp is slice-major (no cross-XCD partial-line write sharing). ----
__global__ __launch_bounds__(256, 8) void k_conv2(
        const unsigned* __restrict__ h2u, const int* __restrict__ srcs,
        const int* __restrict__ off, const int* __restrict__ endp,
        const float* __restrict__ dinv, const float* __restrict__ b2,
        float* __restrict__ tmp, int n, int nb2) {
    int bid = blockIdx.x;
    int slice = (bid & 7) >> 1;
    int idx = ((bid >> 3) << 1) | (bid & 1);
    if (idx >= nb2) return;
    int lane = threadIdx.x & 63;
    bool dup = lane >= 60;                   // lanes 60-63 mirror group 11
    int g = dup ? 11 : lane / 5;
    int f = dup ? (lane - 60) : (lane - g * 5);
    int gb = g * 5;
    size_t R2 = ((size_t)n + 1) * 5;
    const unsigned* base = h2u + (size_t)slice * R2;
    int node = idx * 48 + (threadIdx.x >> 6) * 12 + g;
    if (dup) node = n;
    int nodec = (node < n) ? node : n;
    int j = (node < n) ? off[node] : 0;
    int e = (node < n) ? endp[node] : 0;
    float a0 = 0.f, a1 = 0.f;
    while (__any(j < e)) {
        int sv0 = (j +      f < e) ? srcs[j + f]      : n;
        int sv1 = (j + 5  + f < e) ? srcs[j + 5 + f]  : n;
        int sv2 = (j + 10 + f < e) ? srcs[j + 10 + f] : n;
        int sv3 = (j + 15 + f < e) ? srcs[j + 15 + f] : n;
        #pragma unroll
        for (int k = 0; k < 5; ++k) {
            int s = __shfl(sv0, gb + k);
            unsigned u = base[(size_t)s * 5 + f];
            a0 += bflo(u); a1 += bfhi(u);
        }
        #pragma unroll
        for (int k = 0; k < 5; ++k) {
            int s = __shfl(sv1, gb + k);
            unsigned u = base[(size_t)s * 5 + f];
            a0 += bflo(u); a1 += bfhi(u);
        }
        #pragma unroll
        for (int k = 0; k < 5; ++k) {
            int s = __shfl(sv2, gb + k);
            unsigned u = base[(size_t)s * 5 + f];
            a0 += bflo(u); a1 += bfhi(u);
        }
        #pragma unroll
        for (int k = 0; k < 5; ++k) {
            int s = __shfl(sv3, gb + k);
            unsigned u = base[(size_t)s * 5 + f];
            a0 += bflo(u); a1 += bfhi(u);
        }
        j += 20;
    }
    unsigned us = base[(size_t)nodec * 5 + f];
    float d = (node < n) ? dinv[node] : 0.f;
    float2 bb = ((const float2*)b2)[slice * 5 + f];
    float v0 = d * (a0 + bflo(us)) + bb.x;
    float v1 = d * (a1 + bfhi(us)) + bb.y;
    if (node < n && !dup) {
        float2 o;
        o.x = v0; o.y = v1;
        *(float2*)(tmp + (size_t)slice * ((size_t)n * 10) +
                   (size_t)node * 10 + 2 * f) = o;
    }
}

// ---- log_softmax over the 40 logits of each node (tmp is slice-major) ----
__global__ __launch_bounds__(256) void k_lsm(const float* __restrict__ tmp,
                                             float* __restrict__ out, int n) {
    int t = blockIdx.x * 256 + threadIdx.x;
    int node = t >> 6, lane = t & 63;
    if (node >= n) return;
    size_t nR = (size_t)n * 10;
    float v = -INFINITY;
    if (lane < F_OUT)
        v = tmp[(size_t)(lane / 10) * nR + (size_t)node * 10 + lane % 10];
    float m = v;
    #pragma unroll
    for (int o = 32; o > 0; o >>= 1) m = fmaxf(m, __shfl_xor(m, o));
    float ex = (lane < F_OUT) ? expf(v - m) : 0.f;
    float s = ex;
    #pragma unroll
    for (int o = 32; o > 0; o >>= 1) s += __shfl_xor(s, o);
    float lse = logf(s) + m;
    if (lane < F_OUT) out[(long)node * F_OUT + lane] = v - lse;
}

extern "C" void kernel_launch(void* const* d_in, const int* in_sizes, int n_in,
                              void* d_out, int out_size, void* d_ws, size_t ws_size,
                              hipStream_t stream) {
    const float* x     = (const float*)d_in[0];
    const int*   ei    = (const int*)d_in[1];
    const float* gamma = (const float*)d_in[2];
    const float* beta  = (const float*)d_in[3];
    const float* rmean = (const float*)d_in[4];
    const float* rvar  = (const float*)d_in[5];
    const float* W1    = (const float*)d_in[6];
    const float* b1    = (const float*)d_in[7];
    const float* W2    = (const float*)d_in[8];
    const float* b2    = (const float*)d_in[9];
    float* out = (float*)d_out;

    int n = in_sizes[0] / F_IN;
    int E = in_sizes[1] / 2;
    const int* row = ei;       // edge_index[0] = source
    const int* col = ei + E;   // edge_index[1] = target

    // binning geometry: 256 nodes/bucket, <=512 buckets, <=512 edge chunks
    int NB = (n + 255) >> 8;                          // 391 for n=100K
    int chunk = (E + 511) / 512;
    chunk = (chunk + 255) & ~255;
    if (chunk < 256) chunk = 256;
    int nblk = (E + chunk - 1) / chunk;               // <= 512

    int*   off    = (int*)d_ws;                       // n
    int*   endp   = off + n;                          // n
    float* dinv   = (float*)(endp + n);               // n
    int*   cursor = (int*)(dinv + n);                 // 4 ints
    int*   bb     = cursor + 4;                       // 512 bucket bases
    int*   btot   = bb + 512;                         // 512 bucket totals
    int*   bh     = btot + 512;                       // 512*512 cell table
    int*   srcs   = bh + 512 * 512;                   // E ints
    unsigned* h1u = (unsigned*)(srcs + E);            // 4 regions x (n+1)*8 dwords
    unsigned* hu  = h1u + 4 * (((size_t)n + 1) * 8);  // 4 regions x n*8 (slice-major)
    unsigned* h2u = hu + (size_t)n * 32;              // 4 regions x (n+1)*5 dwords
    float* tmp    = (float*)h1u;      // 4 x n*10 fp32, aliases dead h1u+hu
    unsigned* bpk = hu;               // E dwords, aliases hu (dead until conv1)

    hipMemsetAsync(cursor, 0, 4 * sizeof(int), stream);

    k_hist   <<<nblk, 256, 0, stream>>>(col, E, chunk, nblk, NB, bh);
    k_alloc  <<<NB,   256, 0, stream>>>(bh, bb, btot, cursor, nblk);
    k_scatter<<<nblk, 256, 0, stream>>>(row, col, E, chunk, nblk, NB, bh, bpk);
    k_fine   <<<NB,   256, 0, stream>>>(bpk, bb, btot, off, endp, dinv, srcs, n);

    k_gemm1<<<(n + 63) / 64, 256, 0, stream>>>(x, gamma, beta, rmean, rvar, W1,
                                               dinv, h1u, h2u, n);
    // conv1: 4 slices x nb1 node-blocks (32 nodes each); slice = (bid&7)>>1
    int nb1 = (n + 31) / 32;
    int nb1p = (nb1 + 1) & ~1;                        // even -> grid % 8 == 0
    k_conv1<<<4 * nb1p, 256, 0, stream>>>(h1u, srcs, off, endp, dinv, b1,
                                          hu, n, nb1);
    k_gemm2<<<(n + 63) / 64, 64, 0, stream>>>(hu, W2, dinv, h2u, n);
    // conv2: 4 slices x nb2 node-blocks (48 nodes each); slice = (bid&7)>>1
    int nb2 = (n + 47) / 48;
    int nb2p = (nb2 + 1) & ~1;                        // even -> grid % 8 == 0
    k_conv2<<<4 * nb2p, 256, 0, stream>>>(h2u, srcs, off, endp, dinv, b2,
                                          tmp, n, nb2);
    k_lsm  <<<(n + 3) / 4, 256, 0, stream>>>(tmp, out, n);
}

// Round 9
// 291.301 us; speedup vs baseline: 4.3112x; 1.1203x over previous
//
#include <hip/hip_runtime.h>
#include <hip/hip_bf16.h>
#include <math.h>

#define F_IN 128
#define F_HID 64
#define F_OUT 40
#define BN_EPS 1e-5f

typedef __attribute__((ext_vector_type(8))) short short8;
typedef __attribute__((ext_vector_type(4))) float f32x4;

__device__ __forceinline__ float bflo(unsigned u) { return __uint_as_float(u << 16); }
__device__ __forceinline__ float bfhi(unsigned u) { return __uint_as_float(u & 0xffff0000u); }
__device__ __forceinline__ unsigned pack2(float a, float b) {
    __hip_bfloat162 p;
    p.x = __float2bfloat16(a);
    p.y = __float2bfloat16(b);
    return *(unsigned*)&p;
}

// ============ CSR build via 2-level LDS counting sort.
// r1: global atomics write through memory-side at 32B/op -> never on hot path.
// r4: node reordering destroys L2 residency -> natural order everywhere.
// r6: edge-parallel LDS f32 atomics serialize on the LDS atomic pipe.
// r7/r8: conv geometry rules: (a) per-XCD gather region must be < ~3.5MB
//     (4.0MB thrashes under unroll), (b) rows must be wide/aligned --
//     5-lane 20B rows fragment the TA into 2x segments and 4x srcs passes
//     (69us at 7% HBM / 18% VALU). Best combo: conv1 = 32B rows + 4-batch
//     unroll (3.2MB region holds); conv2 = 40B rows, 2 slices, NO unroll.

// ---- pass 1: per-(bucket, block) coarse histogram ----
__global__ __launch_bounds__(256) void k_hist(const int* __restrict__ col, int E,
                                              int chunk, int nblk, int NB,
                                              int* __restrict__ bh) {
    __shared__ int hist[512];
    int t = threadIdx.x, blk = blockIdx.x;
    for (int i = t; i < NB; i += 256) hist[i] = 0;
    __syncthreads();
    int e0 = blk * chunk, e1 = min(E, e0 + chunk);
    for (int e = e0 + t; e < e1; e += 256)
        atomicAdd(&hist[col[e] >> 8], 1);
    __syncthreads();
    for (int i = t; i < NB; i += 256)
        bh[(size_t)i * nblk + blk] = hist[i];
}

// ---- pass 2: per-bucket scan of its nblk cells; 1 cursor atomic per bucket. ----
__global__ __launch_bounds__(256) void k_alloc(int* __restrict__ bh,
                                               int* __restrict__ bb,
                                               int* __restrict__ bt,
                                               int* __restrict__ cursor, int nblk) {
    int t = threadIdx.x, bu = blockIdx.x;
    int lane = t & 63, wv = t >> 6;
    size_t base_i = (size_t)bu * nblk;
    int i0 = 2 * t, i1 = 2 * t + 1;
    int a = (i0 < nblk) ? bh[base_i + i0] : 0;
    int b = (i1 < nblk) ? bh[base_i + i1] : 0;
    int p = a + b;
    int scan = p;
    #pragma unroll
    for (int o = 1; o < 64; o <<= 1) {
        int tt = __shfl_up(scan, o);
        if (lane >= o) scan += tt;
    }
    __shared__ int wsum[4];
    if (lane == 63) wsum[wv] = scan;
    __syncthreads();
    if (t == 0) {
        int s0 = wsum[0], s1 = wsum[1], s2 = wsum[2], s3 = wsum[3];
        int total = s0 + s1 + s2 + s3;
        int base = atomicAdd(cursor, total);
        bb[bu] = base;
        bt[bu] = total;
        wsum[0] = base; wsum[1] = base + s0;
        wsum[2] = base + s0 + s1; wsum[3] = base + s0 + s1 + s2;
    }
    __syncthreads();
    int excl = wsum[wv] + scan - p;   // absolute start of cell i0
    if (i0 < nblk) bh[base_i + i0] = excl;
    if (i1 < nblk) bh[base_i + i1] = excl + a;
}

// ---- pass 3: scatter edges into bucket-partitioned order via LDS cursors. ----
__global__ __launch_bounds__(256) void k_scatter(const int* __restrict__ row,
                                                 const int* __restrict__ col,
                                                 int E, int chunk, int nblk, int NB,
                                                 const int* __restrict__ bh,
                                                 unsigned* __restrict__ bpk) {
    __shared__ int cur[512];
    int t = threadIdx.x, blk = blockIdx.x;
    for (int i = t; i < NB; i += 256) cur[i] = bh[(size_t)i * nblk + blk];
    __syncthreads();
    int e0 = blk * chunk, e1 = min(E, e0 + chunk);
    for (int e = e0 + t; e < e1; e += 256) {
        int c = col[e];
        int pos = atomicAdd(&cur[c >> 8], 1);
        bpk[pos] = ((unsigned)row[e] << 8) | (unsigned)(c & 255);
    }
}

// ---- pass 4: per-bucket fine histogram + scan -> off/endp/dinv; place srcs. ----
__global__ __launch_bounds__(256) void k_fine(const unsigned* __restrict__ bpk,
                                              const int* __restrict__ bb,
                                              const int* __restrict__ bt,
                                              int* __restrict__ off,
                                              int* __restrict__ endp,
                                              float* __restrict__ dinv,
                                              int* __restrict__ srcs, int n) {
    __shared__ int fine[256];
    __shared__ int wsum[4];
    int t = threadIdx.x, bu = blockIdx.x;
    int lane = t & 63, wv = t >> 6;
    fine[t] = 0;
    __syncthreads();
    int base = bb[bu], tot = bt[bu];
    for (int i = t; i < tot; i += 256)
        atomicAdd(&fine[bpk[base + i] & 255], 1);
    __syncthreads();
    int d = fine[t];
    int scan = d;
    #pragma unroll
    for (int o = 1; o < 64; o <<= 1) {
        int tt = __shfl_up(scan, o);
        if (lane >= o) scan += tt;
    }
    if (lane == 63) wsum[wv] = scan;
    __syncthreads();
    if (t == 0) {
        int s0 = wsum[0], s1 = wsum[1], s2 = wsum[2];
        wsum[0] = 0;
        wsum[1] = s0;
        wsum[2] = s0 + s1;
        wsum[3] = s0 + s1 + s2;
    }
    __syncthreads();
    int o_node = base + wsum[wv] + scan - d;   // absolute segment start
    int node = bu * 256 + t;
    if (node < n) {
        off[node] = o_node;
        endp[node] = o_node + d;
        dinv[node] = rsqrtf((float)d + 1.0f);  // +1 self-loop
    }
    __syncthreads();
    fine[t] = o_node;                          // reuse as cursors
    __syncthreads();
    for (int i = t; i < tot; i += 256) {
        unsigned v = bpk[base + i];
        int pos = atomicAdd(&fine[v & 255], 1);
        srcs[pos] = (int)(v >> 8);
    }
}

// ---- h1' = dinv * (BN(x) @ W1) via MFMA bf16. Block 0 also zeroes the
//      h1u/h2u pad rows (row n) consumed by idle gather lanes. ----
__global__ __launch_bounds__(256) void k_gemm1(
        const float* __restrict__ x, const float* __restrict__ gamma,
        const float* __restrict__ beta, const float* __restrict__ mean,
        const float* __restrict__ var, const float* __restrict__ W1,
        const float* __restrict__ dinv, unsigned* __restrict__ h1u,
        unsigned* __restrict__ h2u, int n) {
    __shared__ unsigned short xt[64 * 136];     // 64 rows x 272B (pad 8 bf16)
    __shared__ float bs[F_IN], bt[F_IN];
    int t = threadIdx.x;
    if (blockIdx.x == 0) {
        size_t R1 = ((size_t)n + 1) * 8;
        size_t R2 = ((size_t)n + 1) * 10;
        if (t < 32) h1u[(size_t)(t >> 3) * R1 + (size_t)n * 8 + (t & 7)] = 0u;
        if (t >= 32 && t < 52) {
            int q = t - 32;
            h2u[(size_t)(q / 10) * R2 + (size_t)n * 10 + (q % 10)] = 0u;
        }
    }
    if (t < F_IN) {
        float s = rsqrtf(var[t] + BN_EPS) * gamma[t];
        bs[t] = s;
        bt[t] = beta[t] - mean[t] * s;
    }
    int lane = t & 63, wv = t >> 6;
    int quad = lane >> 4, c = lane & 15;
    short8 Bf[4][4];
    #pragma unroll
    for (int nt = 0; nt < 4; ++nt)
        #pragma unroll
        for (int ks = 0; ks < 4; ++ks) {
            short8 v;
            #pragma unroll
            for (int j = 0; j < 8; ++j) {
                int k = ks * 32 + quad * 8 + j;
                __hip_bfloat16 hb = __float2bfloat16(W1[k * F_HID + nt * 16 + c]);
                v[j] = *(short*)&hb;
            }
            Bf[nt][ks] = v;
        }
    __syncthreads();                            // bs/bt ready
    int nb = blockIdx.x * 64;
    #pragma unroll
    for (int it = 0; it < 8; ++it) {
        int i = t + 256 * it;                   // float4 slot: 2048 total
        int node = i >> 5, k4 = i & 31;
        int gn = nb + node;
        float4 v = make_float4(0.f, 0.f, 0.f, 0.f);
        if (gn < n) v = *(const float4*)(x + (size_t)gn * F_IN + k4 * 4);
        float4 sv = *(const float4*)(bs + k4 * 4);
        float4 tv = *(const float4*)(bt + k4 * 4);
        unsigned u0 = pack2(v.x * sv.x + tv.x, v.y * sv.y + tv.y);
        unsigned u1 = pack2(v.z * sv.z + tv.z, v.w * sv.w + tv.w);
        *(uint2*)(xt + node * 136 + k4 * 4) = make_uint2(u0, u1);
    }
    __syncthreads();
    const unsigned short* arow = xt + (wv * 16 + c) * 136;
    f32x4 acc[4] = {f32x4{0.f,0.f,0.f,0.f}, f32x4{0.f,0.f,0.f,0.f},
                    f32x4{0.f,0.f,0.f,0.f}, f32x4{0.f,0.f,0.f,0.f}};
    #pragma unroll
    for (int ks = 0; ks < 4; ++ks) {
        short8 af = *(const short8*)(arow + ks * 32 + quad * 8);  // ds_read_b128
        #pragma unroll
        for (int nt = 0; nt < 4; ++nt)
            acc[nt] = __builtin_amdgcn_mfma_f32_16x16x32_bf16(af, Bf[nt][ks],
                                                              acc[nt], 0, 0, 0);
    }
    size_t R1 = ((size_t)n + 1) * 8;
    #pragma unroll
    for (int r = 0; r < 4; ++r) {
        int node = nb + wv * 16 + quad * 4 + r;
        if (node < n) {
            float d = dinv[node];
            #pragma unroll
            for (int nt = 0; nt < 4; ++nt) {
                __hip_bfloat16 hb = __float2bfloat16(acc[nt][r] * d);
                unsigned short* dst =
                    (unsigned short*)(h1u + (size_t)nt * R1 + (size_t)node * 8) + c;
                *dst = *(unsigned short*)&hb;
            }
        }
    }
}

// ---- conv1: natural-order gather, slice pinned to XCD pair (3.2MB region,
//      L2-resident). 8 lanes/node, 4-batch unroll (one latency round/node). ----
__global__ __launch_bounds__(256, 8) void k_conv1(
        const unsigned* __restrict__ h1u, const int* __restrict__ srcs,
        const int* __restrict__ off, const int* __restrict__ endp,
        const float* __restrict__ dinv, const float* __restrict__ b1,
        unsigned* __restrict__ hus, int n, int nb1) {
    int bid = blockIdx.x;
    int slice = (bid & 7) >> 1;
    int idx = ((bid >> 3) << 1) | (bid & 1);
    if (idx >= nb1) return;
    int lane = threadIdx.x & 63;
    int g = lane >> 3, f = lane & 7, gb = g * 8;
    const unsigned* base = h1u + (size_t)slice * (((size_t)n + 1) * 8);
    int node = idx * 32 + (threadIdx.x >> 6) * 8 + g;
    int nodec = (node < n) ? node : n;
    int j = (node < n) ? off[node] : 0;
    int e = (node < n) ? endp[node] : 0;
    float a0 = 0.f, a1 = 0.f;
    while (__any(j < e)) {
        int sv0 = (j +      f < e) ? srcs[j + f]      : n;
        int sv1 = (j + 8  + f < e) ? srcs[j + 8 + f]  : n;
        int sv2 = (j + 16 + f < e) ? srcs[j + 16 + f] : n;
        int sv3 = (j + 24 + f < e) ? srcs[j + 24 + f] : n;
        #pragma unroll
        for (int k = 0; k < 8; ++k) {
            int s = __shfl(sv0, gb + k);
            unsigned u = base[(size_t)s * 8 + f];
            a0 += bflo(u); a1 += bfhi(u);
        }
        #pragma unroll
        for (int k = 0; k < 8; ++k) {
            int s = __shfl(sv1, gb + k);
            unsigned u = base[(size_t)s * 8 + f];
            a0 += bflo(u); a1 += bfhi(u);
        }
        #pragma unroll
        for (int k = 0; k < 8; ++k) {
            int s = __shfl(sv2, gb + k);
            unsigned u = base[(size_t)s * 8 + f];
            a0 += bflo(u); a1 += bfhi(u);
        }
        #pragma unroll
        for (int k = 0; k < 8; ++k) {
            int s = __shfl(sv3, gb + k);
            unsigned u = base[(size_t)s * 8 + f];
            a0 += bflo(u); a1 += bfhi(u);
        }
        j += 32;
    }
    unsigned us = base[(size_t)nodec * 8 + f];
    float d = (node < n) ? dinv[node] : 0.f;
    float2 bb = ((const float2*)b1)[slice * 8 + f];
    float h0 = fmaxf(d * (a0 + bflo(us)) + bb.x, 0.f);
    float h1 = fmaxf(d * (a1 + bfhi(us)) + bb.y, 0.f);
    if (node < n)
        hus[(size_t)slice * ((size_t)n * 8) + (size_t)node * 8 + f] = pack2(h0, h1);
}

// ---- h2' = dinv * (h @ W2); output 2 regions x (n+1)*10 dwords ----
__global__ __launch_bounds__(64) void k_gemm2(
        const unsigned* __restrict__ hus, const float* __restrict__ W2,
        const float* __restrict__ dinv, unsigned* __restrict__ h2u, int n) {
    __shared__ float xl[64 * 66];
    int lane = threadIdx.x;
    int nb = blockIdx.x * 64;
    int tn = lane >> 5;
    int q = lane & 31;
    size_t hN = (size_t)n * 8;
    for (int it = 0; it < 32; ++it) {
        int r = it * 2 + tn;
        int node = nb + r;
        unsigned u = 0;
        if (node < n) u = hus[(size_t)(q >> 3) * hN + (long)node * 8 + (q & 7)];
        xl[r * 66 + 2 * q]     = bflo(u);
        xl[r * 66 + 2 * q + 1] = bfhi(u);
    }
    __syncthreads();
    float acc[F_OUT];
    #pragma unroll
    for (int f = 0; f < F_OUT; ++f) acc[f] = 0.f;
    for (int k = 0; k < F_HID; ++k) {
        float xv = xl[lane * 66 + k];
        const float* wr = W2 + k * F_OUT;
        #pragma unroll
        for (int f = 0; f < F_OUT; ++f) acc[f] = fmaf(xv, wr[f], acc[f]);
    }
    int node = nb + lane;
    if (node < n) {
        float d = dinv[node];
        size_t R2 = ((size_t)n + 1) * 10;
        #pragma unroll
        for (int r = 0; r < 2; ++r)
            #pragma unroll
            for (int t = 0; t < 10; ++t)
                h2u[(size_t)r * R2 + (long)node * 10 + t] =
                    pack2(acc[r * 20 + 2 * t] * d, acc[r * 20 + 2 * t + 1] * d);
    }
}

// ---- conv2: r3-proven geometry. 2 slices x 20 feats (40B rows), slice
//      pinned to XCD quad, 10 lanes/node, NO unroll. ----
__global__ __launch_bounds__(256, 8) void k_conv2(
        const unsigned* __restrict__ h2u, const int* __restrict__ srcs,
        const int* __restrict__ off, const int* __restrict__ endp,
        const float* __restrict__ dinv, const float* __restrict__ b2,
        float* __restrict__ tmp, int n, int nb2) {
    int bid = blockIdx.x;
    int slice = (bid & 7) >> 2;
    int idx = ((bid >> 3) << 2) | (bid & 3);
    if (idx >= nb2) return;
    int lane = threadIdx.x & 63;
    bool lact = lane < 60;
    int g = lane / 10; if (g > 5) g = 5;
    int f = lane % 10;
    int gb = g * 10;
    const unsigned* base = h2u + (size_t)slice * (((size_t)n + 1) * 10);
    int node = idx * 24 + (threadIdx.x >> 6) * 6 + g;
    if (!lact) node = n;
    int nodec = (node < n) ? node : n;
    int j = (node < n) ? off[node] : 0;
    int e = (node < n) ? endp[node] : 0;
    float a0 = 0.f, a1 = 0.f;
    while (__any(j < e)) {
        int cnt = e - j;
        cnt = cnt < 0 ? 0 : (cnt > 10 ? 10 : cnt);
        int srcv = n;
        if (f < cnt && lact) srcv = srcs[j + f];
        #pragma unroll
        for (int k = 0; k < 10; ++k) {
            int s = __shfl(srcv, gb + k);
            unsigned u = base[(long)s * 10 + f];
            a0 += bflo(u);
            a1 += bfhi(u);
        }
        j += cnt;
    }
    unsigned us = base[(long)nodec * 10 + f];
    float d = (node < n) ? dinv[node] : 0.f;
    float2 bb = ((const float2*)b2)[slice * 10 + f];
    float v0 = d * (a0 + bflo(us)) + bb.x;
    float v1 = d * (a1 + bfhi(us)) + bb.y;
    if (node < n && lact) {
        float2 o;
        o.x = v0; o.y = v1;
        *(float2*)(tmp + (long)node * F_OUT + slice * 20 + 2 * f) = o;
    }
}

// ---- log_softmax over the 40 logits of each node; wave per node ----
__global__ __launch_bounds__(256) void k_lsm(const float* __restrict__ tmp,
                                             float* __restrict__ out, int n) {
    int t = blockIdx.x * 256 + threadIdx.x;
    int node = t >> 6, lane = t & 63;
    if (node >= n) return;
    float v = (lane < F_OUT) ? tmp[(long)node * F_OUT + lane] : -INFINITY;
    float m = v;
    #pragma unroll
    for (int o = 32; o > 0; o >>= 1) m = fmaxf(m, __shfl_xor(m, o));
    float ex = (lane < F_OUT) ? expf(v - m) : 0.f;
    float s = ex;
    #pragma unroll
    for (int o = 32; o > 0; o >>= 1) s += __shfl_xor(s, o);
    float lse = logf(s) + m;
    if (lane < F_OUT) out[(long)node * F_OUT + lane] = v - lse;
}

extern "C" void kernel_launch(void* const* d_in, const int* in_sizes, int n_in,
                              void* d_out, int out_size, void* d_ws, size_t ws_size,
                              hipStream_t stream) {
    const float* x     = (const float*)d_in[0];
    const int*   ei    = (const int*)d_in[1];
    const float* gamma = (const float*)d_in[2];
    const float* beta  = (const float*)d_in[3];
    const float* rmean = (const float*)d_in[4];
    const float* rvar  = (const float*)d_in[5];
    const float* W1    = (const float*)d_in[6];
    const float* b1    = (const float*)d_in[7];
    const float* W2    = (const float*)d_in[8];
    const float* b2    = (const float*)d_in[9];
    float* out = (float*)d_out;

    int n = in_sizes[0] / F_IN;
    int E = in_sizes[1] / 2;
    const int* row = ei;       // edge_index[0] = source
    const int* col = ei + E;   // edge_index[1] = target

    // binning geometry: 256 nodes/bucket, <=512 buckets, <=512 edge chunks
    int NB = (n + 255) >> 8;                          // 391 for n=100K
    int chunk = (E + 511) / 512;
    chunk = (chunk + 255) & ~255;
    if (chunk < 256) chunk = 256;
    int nblk = (E + chunk - 1) / chunk;               // <= 512

    int*   off    = (int*)d_ws;                       // n
    int*   endp   = off + n;                          // n
    float* dinv   = (float*)(endp + n);               // n
    int*   cursor = (int*)(dinv + n);                 // 4 ints
    int*   bb     = cursor + 4;                       // 512 bucket bases
    int*   btot   = bb + 512;                         // 512 bucket totals
    int*   bh     = btot + 512;                       // 512*512 cell table
    int*   srcs   = bh + 512 * 512;                   // E ints
    unsigned* h1u = (unsigned*)(srcs + E);            // 4 regions x (n+1)*8 dwords
    unsigned* hu  = h1u + 4 * (((size_t)n + 1) * 8);  // 4 regions x n*8 (slice-major)
    unsigned* h2u = hu + (size_t)n * 32;              // 2 regions x (n+1)*10 dwords
    float* tmp    = (float*)h1u;      // n*40 fp32, aliases dead h1u+hu
    unsigned* bpk = hu;               // E dwords, aliases hu (dead until conv1)

    hipMemsetAsync(cursor, 0, 4 * sizeof(int), stream);

    k_hist   <<<nblk, 256, 0, stream>>>(col, E, chunk, nblk, NB, bh);
    k_alloc  <<<NB,   256, 0, stream>>>(bh, bb, btot, cursor, nblk);
    k_scatter<<<nblk, 256, 0, stream>>>(row, col, E, chunk, nblk, NB, bh, bpk);
    k_fine   <<<NB,   256, 0, stream>>>(bpk, bb, btot, off, endp, dinv, srcs, n);

    k_gemm1<<<(n + 63) / 64, 256, 0, stream>>>(x, gamma, beta, rmean, rvar, W1,
                                               dinv, h1u, h2u, n);
    // conv1: 4 slices x nb1 node-blocks (32 nodes each); slice = (bid&7)>>1
    int nb1 = (n + 31) / 32;
    int nb1p = (nb1 + 1) & ~1;                        // even -> grid % 8 == 0
    k_conv1<<<4 * nb1p, 256, 0, stream>>>(h1u, srcs, off, endp, dinv, b1,
                                          hu, n, nb1);
    k_gemm2<<<(n + 63) / 64, 64, 0, stream>>>(hu, W2, dinv, h2u, n);
    // conv2: 2 slices x nb2 node-blocks (24 nodes each); slice = (bid&7)>>2
    int nb2 = (n + 23) / 24;
    int nb2p = (nb2 + 3) & ~3;                        // mult of 4 -> grid % 8 == 0
    k_conv2<<<2 * nb2p, 256, 0, stream>>>(h2u, srcs, off, endp, dinv, b2,
                                          tmp, n, nb2);
    k_lsm  <<<(n + 3) / 4, 256, 0, stream>>>(tmp, out, n);
}